// Round 1
// baseline (3982.393 us; speedup 1.0000x reference)
//
#include <hip/hip_runtime.h>
#include <hip/hip_bf16.h>
#include <math.h>

#define SEQ 2048
#define DIM 768
#define NHEADS 6
#define NKVH 2
#define HDIM 128
#define VOC 32768
#define FFN 3072

typedef unsigned short u16;
using bf16x8 = __attribute__((ext_vector_type(8))) short;
using f32x4  = __attribute__((ext_vector_type(4))) float;

__device__ __forceinline__ u16 f2bf(float f){
  union { float f; unsigned u; } x; x.f = f;
  unsigned r = x.u + 0x7FFFu + ((x.u >> 16) & 1u);
  return (u16)(r >> 16);
}

__device__ __forceinline__ f32x4 mfma16(bf16x8 a, bf16x8 b, f32x4 c){
  return __builtin_amdgcn_mfma_f32_16x16x32_bf16(a, b, c, 0, 0, 0);
}

__device__ __forceinline__ float blockReduceSum(float v){
  __shared__ float tmp[4];
  #pragma unroll
  for (int off = 32; off > 0; off >>= 1) v += __shfl_xor(v, off);
  __syncthreads();
  if ((threadIdx.x & 63) == 0) tmp[threadIdx.x >> 6] = v;
  __syncthreads();
  return tmp[0] + tmp[1] + tmp[2] + tmp[3];
}

__global__ void rope_tables_kernel(float* __restrict__ cosT, float* __restrict__ sinT){
  int i = blockIdx.x * 256 + threadIdx.x;
  int t = i >> 6, j = i & 63;
  float inv = (float)(1.0 / pow(100000.0, (double)(2 * j) / 128.0));
  float fr = (float)t * inv;
  cosT[i] = cosf(fr);
  sinT[i] = sinf(fr);
}

__global__ __launch_bounds__(256)
void embed_kernel(const int* __restrict__ idx, const float* __restrict__ wte,
                  const float* __restrict__ sgw, const float* __restrict__ slam,
                  float* __restrict__ x, float* __restrict__ x0){
  int t = blockIdx.x;
  int tok  = idx[t];
  int tokp = idx[t > 0 ? t - 1 : 0];
  float e[3], ep[3];
  float ss = 0.f, ssp = 0.f;
  #pragma unroll
  for (int i = 0; i < 3; ++i){
    int d = threadIdx.x + i * 256;
    e[i]  = wte[(size_t)tok  * DIM + d];
    ep[i] = wte[(size_t)tokp * DIM + d];
    ss  += e[i] * e[i];
    ssp += ep[i] * ep[i];
  }
  ss  = blockReduceSum(ss);
  ssp = blockReduceSum(ssp);
  float s1 = rsqrtf(ss  / (float)DIM + 1e-6f);
  float s2 = rsqrtf(ssp / (float)DIM + 1e-6f);
  float gp = (threadIdx.x < 24) ? e[0] * s1 * sgw[threadIdx.x] : 0.f;
  gp = blockReduceSum(gp);
  float smear = slam[0] / (1.f + __expf(-gp));
  #pragma unroll
  for (int i = 0; i < 3; ++i){
    int d = threadIdx.x + i * 256;
    float val = e[i] * s1 + smear * (ep[i] * s2);
    x [(size_t)t * DIM + d] = val;
    x0[(size_t)t * DIM + d] = val;
  }
}

__global__ __launch_bounds__(256)
void resid_rms_kernel(float* __restrict__ x, const float* __restrict__ x0,
                      const float* __restrict__ rls, const float* __restrict__ xls,
                      int layer, int mode, u16* __restrict__ h, float* __restrict__ h12){
  int t = blockIdx.x;
  float rl = mode ? 1.f : rls[layer];
  float xl = mode ? 0.f : xls[layer];
  float v[3]; float ss = 0.f;
  #pragma unroll
  for (int i = 0; i < 3; ++i){
    int d = threadIdx.x + i * 256;
    float val = rl * x[(size_t)t * DIM + d] + xl * x0[(size_t)t * DIM + d];
    v[i] = val; ss += val * val;
  }
  ss = blockReduceSum(ss);
  float sc = rsqrtf(ss / (float)DIM + 1e-6f);
  #pragma unroll
  for (int i = 0; i < 3; ++i){
    int d = threadIdx.x + i * 256;
    if (!mode) x[(size_t)t * DIM + d] = v[i];
    h[(size_t)t * DIM + d] = f2bf(v[i] * sc);
  }
  if (!mode && threadIdx.x < 12) h12[t * 12 + threadIdx.x] = v[0] * sc;
}

// C[M,N] = A(bf16, MxK) @ B(fp32, NxK)^T.  EPI: 0 store f32, 1 accumulate f32,
// 2 relu^2 -> bf16, 3 softcap -> f32, 4 QKV pointer-select -> f32 (ldc=1280)
template<int EPI>
__global__ __launch_bounds__(256)
void gemm_bt(const u16* __restrict__ A, const float* __restrict__ Bq,
             const float* __restrict__ Bk2, const float* __restrict__ Bv2,
             void* __restrict__ Cout, int M, int N, int K, int ldc){
  __shared__ __align__(16) u16 As[128][72];
  __shared__ __align__(16) u16 Bs[128][72];
  int tid = threadIdx.x, lane = tid & 63, w = tid >> 6;
  int l15 = lane & 15, l4 = lane >> 4;
  int bm = blockIdx.y * 128, bn = blockIdx.x * 128;
  const float* B = Bq; int nb = bn;
  if (EPI == 4){
    if (blockIdx.x >= 8){ B = Bv2; nb = (blockIdx.x - 8) * 128; }
    else if (blockIdx.x >= 6){ B = Bk2; nb = (blockIdx.x - 6) * 128; }
  }
  f32x4 acc[4][4] = {};
  int wm = (w >> 1) * 64, wn = (w & 1) * 64;
  for (int k0 = 0; k0 < K; k0 += 64){
    #pragma unroll
    for (int it = 0; it < 4; ++it){
      int p = tid + it * 256, r = p >> 3, cc = (p & 7) * 8;
      *(uint4*)&As[r][cc] = *(const uint4*)&A[(size_t)(bm + r) * K + k0 + cc];
    }
    #pragma unroll
    for (int it = 0; it < 4; ++it){
      int p = tid + it * 256, r = p >> 3, cc = (p & 7) * 8;
      const float* s = &B[(size_t)(nb + r) * K + k0 + cc];
      float4 f0 = *(const float4*)s;
      float4 f1 = *(const float4*)(s + 4);
      uint4 pk;
      pk.x = (unsigned)f2bf(f0.x) | ((unsigned)f2bf(f0.y) << 16);
      pk.y = (unsigned)f2bf(f0.z) | ((unsigned)f2bf(f0.w) << 16);
      pk.z = (unsigned)f2bf(f1.x) | ((unsigned)f2bf(f1.y) << 16);
      pk.w = (unsigned)f2bf(f1.z) | ((unsigned)f2bf(f1.w) << 16);
      *(uint4*)&Bs[r][cc] = pk;
    }
    __syncthreads();
    #pragma unroll
    for (int kk = 0; kk < 2; ++kk){
      bf16x8 a[4], b[4];
      #pragma unroll
      for (int i = 0; i < 4; ++i){
        a[i] = *(const bf16x8*)&As[wm + i * 16 + l15][kk * 32 + l4 * 8];
        b[i] = *(const bf16x8*)&Bs[wn + i * 16 + l15][kk * 32 + l4 * 8];
      }
      #pragma unroll
      for (int m = 0; m < 4; ++m)
        #pragma unroll
        for (int n = 0; n < 4; ++n)
          acc[m][n] = mfma16(a[m], b[n], acc[m][n]);
    }
    __syncthreads();
  }
  float* Cf = (float*)Cout;
  u16*   Cb = (u16*)Cout;
  #pragma unroll
  for (int m = 0; m < 4; ++m)
  #pragma unroll
  for (int n = 0; n < 4; ++n){
    int row0 = bm + wm + m * 16 + l4 * 4;
    int col  = bn + wn + n * 16 + l15;
    #pragma unroll
    for (int r = 0; r < 4; ++r){
      size_t off = (size_t)(row0 + r) * ldc + col;
      float v = acc[m][n][r];
      if (EPI == 0 || EPI == 4) Cf[off] = v;
      else if (EPI == 1) Cf[off] += v;
      else if (EPI == 2){ float tt = fmaxf(v, 0.f); Cb[off] = f2bf(tt * tt); }
      else if (EPI == 3) Cf[off] = 15.f * tanhf(v * (1.f / 15.f));
    }
  }
}

__global__ __launch_bounds__(256)
void rope_prep_kernel(const float* __restrict__ qkv, const float* __restrict__ cosT,
                      const float* __restrict__ sinT, u16* __restrict__ qb,
                      u16* __restrict__ kb, u16* __restrict__ vb,
                      const float* __restrict__ h12, const float* __restrict__ vgw,
                      const float* __restrict__ ve_emb, const int* __restrict__ idx, int ve){
  int t = blockIdx.x, tid = threadIdx.x;
  int lane = tid & 63, w = tid >> 6;
  const float* row = qkv + (size_t)t * 1280;
  float c = cosT[t * 64 + lane], s = sinT[t * 64 + lane];
  #pragma unroll
  for (int ii = 0; ii < 2; ++ii){
    int item = w + ii * 4;
    const float* src; u16* dst;
    if (item < 6){ src = row + item * HDIM; dst = qb + (size_t)t * DIM + item * HDIM; }
    else { src = row + DIM + (item - 6) * HDIM; dst = kb + (size_t)t * (NKVH * HDIM) + (item - 6) * HDIM; }
    float x1 = src[lane], x2 = src[64 + lane];
    float o1 =  x1 * c + x2 * s;
    float o2 = -x1 * s + x2 * c;
    float ss = o1 * o1 + o2 * o2;
    #pragma unroll
    for (int off = 1; off < 64; off <<= 1) ss += __shfl_xor(ss, off);
    float sc = rsqrtf(ss / (float)HDIM + 1e-6f) * 1.2f;
    dst[lane]      = f2bf(o1 * sc);
    dst[64 + lane] = f2bf(o2 * sc);
  }
  int kvh = tid >> 7, d = tid & 127;
  float val = row[1024 + kvh * HDIM + d];
  if (ve >= 0){
    float g = 0.f;
    #pragma unroll
    for (int j = 0; j < 12; ++j) g += h12[t * 12 + j] * vgw[(ve * 2 + kvh) * 12 + j];
    g = 3.f / (1.f + __expf(-g));
    val += g * ve_emb[((size_t)ve * VOC + idx[t]) * (size_t)(NKVH * HDIM) + kvh * HDIM + d];
  }
  vb[(size_t)t * (NKVH * HDIM) + kvh * HDIM + d] = f2bf(val);
}

__global__ __launch_bounds__(256)
void attn_kernel(const u16* __restrict__ qb, const u16* __restrict__ kb,
                 const u16* __restrict__ vb, u16* __restrict__ yb, int window){
  __shared__ __align__(16) u16 Ks[64][136];
  __shared__ __align__(16) u16 Vt[128][72];
  __shared__ __align__(16) u16 Ps[4][16][72];
  int tid = threadIdx.x, lane = tid & 63, w = tid >> 6;
  int l15 = lane & 15, l4 = lane >> 4;
  int h = blockIdx.y, kvh = h / 3;
  int qs = blockIdx.x * 64;
  bf16x8 qf[4];
  #pragma unroll
  for (int kk = 0; kk < 4; ++kk)
    qf[kk] = *(const bf16x8*)&qb[(size_t)(qs + w * 16 + l15) * DIM + h * HDIM + kk * 32 + l4 * 8];
  f32x4 o[8] = {};
  float m[4]    = {-INFINITY, -INFINITY, -INFINITY, -INFINITY};
  float lsum[4] = {0.f, 0.f, 0.f, 0.f};
  int c0 = 0;
  if (window > 0){ int jm = qs - window; if (jm > 0) c0 = jm >> 6; }
  int c1 = qs >> 6;
  const float scale = 0.08838834764831845f;  // 1/sqrt(128)
  for (int cg = c0; cg <= c1; ++cg){
    int j0 = cg * 64;
    __syncthreads();
    #pragma unroll
    for (int it = 0; it < 4; ++it){
      int p = tid + it * 256, r = p >> 4, cc = (p & 15) * 8;
      *(uint4*)&Ks[r][cc] = *(const uint4*)&kb[(size_t)(j0 + r) * (NKVH * HDIM) + kvh * HDIM + cc];
    }
    {
      int key = tid >> 2, d0 = (tid & 3) * 32;
      const uint4* s4 = (const uint4*)&vb[(size_t)(j0 + key) * (NKVH * HDIM) + kvh * HDIM + d0];
      #pragma unroll
      for (int qq = 0; qq < 4; ++qq){
        uint4 vvv = s4[qq];
        const u16* us = (const u16*)&vvv;
        #pragma unroll
        for (int dd = 0; dd < 8; ++dd) Vt[d0 + qq * 8 + dd][key] = us[dd];
      }
    }
    __syncthreads();
    f32x4 sA[4] = {};
    #pragma unroll
    for (int kk = 0; kk < 4; ++kk){
      #pragma unroll
      for (int n = 0; n < 4; ++n){
        bf16x8 b = *(const bf16x8*)&Ks[n * 16 + l15][kk * 32 + l4 * 8];
        sA[n] = mfma16(qf[kk], b, sA[n]);
      }
    }
    #pragma unroll
    for (int r = 0; r < 4; ++r){
      int qrow = qs + w * 16 + l4 * 4 + r;
      float rowmax = -1e30f;
      #pragma unroll
      for (int n = 0; n < 4; ++n){
        int key = j0 + n * 16 + l15;
        bool ok = (key <= qrow) && (window < 0 || (qrow - key) <= window);
        float sv = ok ? sA[n][r] * scale : -1e30f;
        sA[n][r] = sv;
        rowmax = fmaxf(rowmax, sv);
      }
      #pragma unroll
      for (int off = 1; off < 16; off <<= 1) rowmax = fmaxf(rowmax, __shfl_xor(rowmax, off));
      float mn = fmaxf(m[r], rowmax);
      float alpha = __expf(m[r] - mn);
      float rs = 0.f;
      #pragma unroll
      for (int n = 0; n < 4; ++n){
        float pp = __expf(sA[n][r] - mn);
        sA[n][r] = pp;
        rs += pp;
      }
      #pragma unroll
      for (int off = 1; off < 16; off <<= 1) rs += __shfl_xor(rs, off);
      lsum[r] = lsum[r] * alpha + rs;
      m[r] = mn;
      #pragma unroll
      for (int dt = 0; dt < 8; ++dt) o[dt][r] *= alpha;
    }
    #pragma unroll
    for (int n = 0; n < 4; ++n)
      #pragma unroll
      for (int r = 0; r < 4; ++r)
        Ps[w][l4 * 4 + r][n * 16 + l15] = f2bf(sA[n][r]);
    __syncthreads();
    #pragma unroll
    for (int kk = 0; kk < 2; ++kk){
      bf16x8 a = *(const bf16x8*)&Ps[w][l15][kk * 32 + l4 * 8];
      #pragma unroll
      for (int dt = 0; dt < 8; ++dt){
        bf16x8 b = *(const bf16x8*)&Vt[dt * 16 + l15][kk * 32 + l4 * 8];
        o[dt] = mfma16(a, b, o[dt]);
      }
    }
  }
  #pragma unroll
  for (int dt = 0; dt < 8; ++dt)
    #pragma unroll
    for (int r = 0; r < 4; ++r){
      int rowg = qs + w * 16 + l4 * 4 + r;
      int col  = h * HDIM + dt * 16 + l15;
      yb[(size_t)rowg * DIM + col] = f2bf(o[dt][r] / lsum[r]);
    }
}

__global__ __launch_bounds__(256)
void final_rms_kernel(const float* __restrict__ x, const float* __restrict__ xb,
                      const float* __restrict__ blam, u16* __restrict__ h){
  int t = blockIdx.x;
  float bl = blam[0];
  float v[3], ss = 0.f;
  #pragma unroll
  for (int i = 0; i < 3; ++i){
    int d = threadIdx.x + i * 256;
    float val = x[(size_t)t * DIM + d] - bl * xb[(size_t)t * DIM + d];
    v[i] = val; ss += val * val;
  }
  ss = blockReduceSum(ss);
  float sc = rsqrtf(ss / (float)DIM + 1e-6f);
  #pragma unroll
  for (int i = 0; i < 3; ++i){
    int d = threadIdx.x + i * 256;
    h[(size_t)t * DIM + d] = f2bf(v[i] * sc);
  }
}

__global__ void copy_kernel(const float4* __restrict__ s, float4* __restrict__ d){
  int i = blockIdx.x * 256 + threadIdx.x;
  d[i] = s[i];
}

extern "C" void kernel_launch(void* const* d_in, const int* in_sizes, int n_in,
                              void* d_out, int out_size, void* d_ws, size_t ws_size,
                              hipStream_t stream){
  const int*   idx  = (const int*)  d_in[0];
  const float* wte  = (const float*)d_in[1];
  const float* q_w  = (const float*)d_in[2];
  const float* k_w  = (const float*)d_in[3];
  const float* v_w  = (const float*)d_in[4];
  const float* apw  = (const float*)d_in[5];
  const float* vgw  = (const float*)d_in[6];
  const float* fcw  = (const float*)d_in[7];
  const float* mpw  = (const float*)d_in[8];
  const float* vemb = (const float*)d_in[9];
  const float* lmw  = (const float*)d_in[10];
  const float* rls  = (const float*)d_in[11];
  const float* xls  = (const float*)d_in[12];
  const float* sgw  = (const float*)d_in[13];
  const float* slam = (const float*)d_in[14];
  const float* blam = (const float*)d_in[15];

  char* p = (char*)d_ws;
  auto alloc = [&](size_t bytes)->char*{
    char* r = p; p += (bytes + 255) & ~(size_t)255; return r;
  };
  float* cosT = (float*)alloc((size_t)SEQ * 64 * 4);
  float* sinT = (float*)alloc((size_t)SEQ * 64 * 4);
  float* x    = (float*)alloc((size_t)SEQ * DIM * 4);
  float* x0   = (float*)alloc((size_t)SEQ * DIM * 4);
  float* xb   = (float*)alloc((size_t)SEQ * DIM * 4);
  float* qkv  = (float*)alloc((size_t)SEQ * 1280 * 4);
  float* h12  = (float*)alloc((size_t)SEQ * 12 * 4);
  u16* h   = (u16*)alloc((size_t)SEQ * DIM * 2);
  u16* qb  = (u16*)alloc((size_t)SEQ * DIM * 2);
  u16* kb  = (u16*)alloc((size_t)SEQ * NKVH * HDIM * 2);
  u16* vb  = (u16*)alloc((size_t)SEQ * NKVH * HDIM * 2);
  u16* yb  = (u16*)alloc((size_t)SEQ * DIM * 2);
  u16* act = (u16*)alloc((size_t)SEQ * FFN * 2);

  rope_tables_kernel<<<SEQ * 64 / 256, 256, 0, stream>>>(cosT, sinT);
  embed_kernel<<<SEQ, 256, 0, stream>>>(idx, wte, sgw, slam, x, x0);

  static const int WINDOWS[12] = {512, 512, 512, -1, 512, 512, 512, -1, 512, 512, 512, -1};
  for (int l = 0; l < 12; ++l){
    resid_rms_kernel<<<SEQ, 256, 0, stream>>>(x, x0, rls, xls, l, 0, h, h12);
    gemm_bt<4><<<dim3(10, 16), 256, 0, stream>>>(h, q_w + (size_t)l * DIM * DIM,
        k_w + (size_t)l * NKVH * HDIM * DIM, v_w + (size_t)l * NKVH * HDIM * DIM,
        qkv, SEQ, 1280, DIM, 1280);
    int ve = (l & 1) ? (l >> 1) : -1;
    rope_prep_kernel<<<SEQ, 256, 0, stream>>>(qkv, cosT, sinT, qb, kb, vb, h12, vgw, vemb, idx, ve);
    attn_kernel<<<dim3(SEQ / 64, NHEADS), 256, 0, stream>>>(qb, kb, vb, yb, WINDOWS[l]);
    gemm_bt<1><<<dim3(DIM / 128, 16), 256, 0, stream>>>(yb, apw + (size_t)l * DIM * DIM,
        nullptr, nullptr, x, SEQ, DIM, DIM, DIM);
    resid_rms_kernel<<<SEQ, 256, 0, stream>>>(x, x0, rls, xls, l, 1, h, h12);
    gemm_bt<2><<<dim3(FFN / 128, 16), 256, 0, stream>>>(h, fcw + (size_t)l * FFN * DIM,
        nullptr, nullptr, act, SEQ, FFN, DIM, FFN);
    gemm_bt<1><<<dim3(DIM / 128, 16), 256, 0, stream>>>(act, mpw + (size_t)l * DIM * FFN,
        nullptr, nullptr, x, SEQ, DIM, FFN, DIM);
    if (l == 5) copy_kernel<<<(SEQ * DIM / 4) / 256, 256, 0, stream>>>((const float4*)x, (float4*)xb);
  }
  final_rms_kernel<<<SEQ, 256, 0, stream>>>(x, xb, blam, h);
  gemm_bt<3><<<dim3(VOC / 128, 16), 256, 0, stream>>>(h, lmw, nullptr, nullptr,
      d_out, SEQ, VOC, DIM, VOC);
}

// Round 3
// 2763.988 us; speedup vs baseline: 1.4408x; 1.4408x over previous
//
#include <hip/hip_runtime.h>
#include <hip/hip_bf16.h>
#include <math.h>

#define SEQ 2048
#define DIM 768
#define NHEADS 6
#define NKVH 2
#define HDIM 128
#define VOC 32768
#define FFN 3072

typedef unsigned short u16;
using bf16x8 = __attribute__((ext_vector_type(8))) short;
using f32x4  = __attribute__((ext_vector_type(4))) float;

__device__ __forceinline__ u16 f2bf(float f){
  union { float f; unsigned u; } x; x.f = f;
  unsigned r = x.u + 0x7FFFu + ((x.u >> 16) & 1u);
  return (u16)(r >> 16);
}

__device__ __forceinline__ f32x4 mfma16(bf16x8 a, bf16x8 b, f32x4 c){
  return __builtin_amdgcn_mfma_f32_16x16x32_bf16(a, b, c, 0, 0, 0);
}

__device__ __forceinline__ void async16(const void* g, void* l){
  __builtin_amdgcn_global_load_lds((const __attribute__((address_space(1))) void*)g,
                                   (__attribute__((address_space(3))) void*)l, 16, 0, 0);
}

__device__ __forceinline__ float blockReduceSum(float v){
  __shared__ float tmp[4];
  #pragma unroll
  for (int off = 32; off > 0; off >>= 1) v += __shfl_xor(v, off);
  __syncthreads();
  if ((threadIdx.x & 63) == 0) tmp[threadIdx.x >> 6] = v;
  __syncthreads();
  return tmp[0] + tmp[1] + tmp[2] + tmp[3];
}

__global__ void rope_tables_kernel(float* __restrict__ cosT, float* __restrict__ sinT){
  int i = blockIdx.x * 256 + threadIdx.x;
  int t = i >> 6, j = i & 63;
  float inv = (float)(1.0 / pow(100000.0, (double)(2 * j) / 128.0));
  float fr = (float)t * inv;
  cosT[i] = cosf(fr);
  sinT[i] = sinf(fr);
}

// fp32 -> bf16 weight conversion; handles per-layer packing via dstPitch/dstOff.
__global__ __launch_bounds__(256)
void convert_kernel(const float* __restrict__ src, u16* __restrict__ dst,
                    int perSrc, int dstPitch, int dstOff, int total8){
  int i = blockIdx.x * 256 + threadIdx.x;
  if (i >= total8) return;
  int e = i * 8;
  int layer = e / perSrc;
  int rem = e - layer * perSrc;
  const float4* s = (const float4*)(src + (size_t)e);
  float4 f0 = s[0], f1 = s[1];
  uint4 pk;
  pk.x = (unsigned)f2bf(f0.x) | ((unsigned)f2bf(f0.y) << 16);
  pk.y = (unsigned)f2bf(f0.z) | ((unsigned)f2bf(f0.w) << 16);
  pk.z = (unsigned)f2bf(f1.x) | ((unsigned)f2bf(f1.y) << 16);
  pk.w = (unsigned)f2bf(f1.z) | ((unsigned)f2bf(f1.w) << 16);
  *(uint4*)(dst + (size_t)layer * dstPitch + dstOff + rem) = pk;
}

__global__ __launch_bounds__(256)
void embed_kernel(const int* __restrict__ idx, const float* __restrict__ wte,
                  const float* __restrict__ sgw, const float* __restrict__ slam,
                  float* __restrict__ x, float* __restrict__ x0){
  int t = blockIdx.x;
  int tok  = idx[t];
  int tokp = idx[t > 0 ? t - 1 : 0];
  float e[3], ep[3];
  float ss = 0.f, ssp = 0.f;
  #pragma unroll
  for (int i = 0; i < 3; ++i){
    int d = threadIdx.x + i * 256;
    e[i]  = wte[(size_t)tok  * DIM + d];
    ep[i] = wte[(size_t)tokp * DIM + d];
    ss  += e[i] * e[i];
    ssp += ep[i] * ep[i];
  }
  ss  = blockReduceSum(ss);
  ssp = blockReduceSum(ssp);
  float s1 = rsqrtf(ss  / (float)DIM + 1e-6f);
  float s2 = rsqrtf(ssp / (float)DIM + 1e-6f);
  float gp = (threadIdx.x < 24) ? e[0] * s1 * sgw[threadIdx.x] : 0.f;
  gp = blockReduceSum(gp);
  float smear = slam[0] / (1.f + __expf(-gp));
  #pragma unroll
  for (int i = 0; i < 3; ++i){
    int d = threadIdx.x + i * 256;
    float val = e[i] * s1 + smear * (ep[i] * s2);
    x [(size_t)t * DIM + d] = val;
    x0[(size_t)t * DIM + d] = val;
  }
}

// mode 0: x = rl*(x + sum(partials)) + xl*x0 ; h=rms(x) ; h12
// mode 1: x = x + sum(partials) ; h=rms(x)
__global__ __launch_bounds__(256)
void resid_rms_kernel(float* __restrict__ x, const float* __restrict__ x0,
                      const float* __restrict__ rls, const float* __restrict__ xls,
                      int layer, int mode, u16* __restrict__ h, float* __restrict__ h12,
                      const float* __restrict__ part, int nparts){
  int t = blockIdx.x;
  float rl = mode ? 1.f : rls[layer];
  float xl = mode ? 0.f : xls[layer];
  float v[3]; float ss = 0.f;
  #pragma unroll
  for (int i = 0; i < 3; ++i){
    int d = threadIdx.x + i * 256;
    size_t o = (size_t)t * DIM + d;
    float val = x[o];
    for (int p = 0; p < nparts; ++p) val += part[(size_t)p * SEQ * DIM + o];
    val = rl * val + xl * x0[o];
    v[i] = val; ss += val * val;
  }
  ss = blockReduceSum(ss);
  float sc = rsqrtf(ss / (float)DIM + 1e-6f);
  #pragma unroll
  for (int i = 0; i < 3; ++i){
    int d = threadIdx.x + i * 256;
    size_t o = (size_t)t * DIM + d;
    x[o] = v[i];
    h[o] = f2bf(v[i] * sc);
  }
  if (!mode && threadIdx.x < 12) h12[t * 12 + threadIdx.x] = v[0] * sc;
}

// C[M,N] = A(bf16 MxK) @ B^T.  BSRC=1: B bf16 (global_load_lds staging, linear LDS)
// BSRC=0: B fp32 (reg-staged convert, padded LDS).  Split-K via gridDim.z ->
// partial f32 planes at Cout + z*M*ldc (EPI 0 only).
// EPI: 0 store f32, 2 relu^2 -> bf16, 3 softcap -> f32
template<int EPI, int BSRC>
__global__ __launch_bounds__(256)
void gemm_k(const u16* __restrict__ A, const void* __restrict__ Bvp,
            void* __restrict__ Cout, int M, int N, int K, int ldc){
  constexpr int LDT = BSRC ? 64 : 72;
  __shared__ __align__(16) u16 As[128 * LDT];
  __shared__ __align__(16) u16 Bs[128 * LDT];
  int tid = threadIdx.x, lane = tid & 63, w = tid >> 6;
  int l15 = lane & 15, l4 = lane >> 4;
  int bm = blockIdx.y * 128, bn = blockIdx.x * 128;
  int kPer = K / (int)gridDim.z;
  int k0beg = blockIdx.z * kPer, k0end = k0beg + kPer;
  f32x4 acc[4][4] = {};
  int wm = (w >> 1) * 64, wn = (w & 1) * 64;
  for (int k0 = k0beg; k0 < k0end; k0 += 64){
    if constexpr (BSRC){
      const u16* B = (const u16*)Bvp;
      #pragma unroll
      for (int i = 0; i < 4; ++i){
        int e = (w * 4 + i) * 512 + lane * 8;
        int r = e >> 6, c = e & 63;
        async16(&A[(size_t)(bm + r) * K + k0 + c], &As[(w * 4 + i) * 512]);
        async16(&B[(size_t)(bn + r) * K + k0 + c], &Bs[(w * 4 + i) * 512]);
      }
    } else {
      const float* B = (const float*)Bvp;
      #pragma unroll
      for (int it = 0; it < 4; ++it){
        int p = tid + it * 256, r = p >> 3, cc = (p & 7) * 8;
        *(uint4*)&As[r * LDT + cc] = *(const uint4*)&A[(size_t)(bm + r) * K + k0 + cc];
      }
      #pragma unroll
      for (int it = 0; it < 4; ++it){
        int p = tid + it * 256, r = p >> 3, cc = (p & 7) * 8;
        const float* s = &B[(size_t)(bn + r) * K + k0 + cc];
        float4 f0 = *(const float4*)s;
        float4 f1 = *(const float4*)(s + 4);
        uint4 pk;
        pk.x = (unsigned)f2bf(f0.x) | ((unsigned)f2bf(f0.y) << 16);
        pk.y = (unsigned)f2bf(f0.z) | ((unsigned)f2bf(f0.w) << 16);
        pk.z = (unsigned)f2bf(f1.x) | ((unsigned)f2bf(f1.y) << 16);
        pk.w = (unsigned)f2bf(f1.z) | ((unsigned)f2bf(f1.w) << 16);
        *(uint4*)&Bs[r * LDT + cc] = pk;
      }
    }
    __syncthreads();
    #pragma unroll
    for (int kk = 0; kk < 2; ++kk){
      bf16x8 a[4], b[4];
      #pragma unroll
      for (int i = 0; i < 4; ++i){
        a[i] = *(const bf16x8*)&As[(wm + i * 16 + l15) * LDT + kk * 32 + l4 * 8];
        b[i] = *(const bf16x8*)&Bs[(wn + i * 16 + l15) * LDT + kk * 32 + l4 * 8];
      }
      #pragma unroll
      for (int m = 0; m < 4; ++m)
        #pragma unroll
        for (int n = 0; n < 4; ++n)
          acc[m][n] = mfma16(a[m], b[n], acc[m][n]);
    }
    __syncthreads();
  }
  float* Cf = (float*)Cout + (EPI == 0 ? (size_t)blockIdx.z * M * ldc : 0);
  u16*   Cb = (u16*)Cout;
  #pragma unroll
  for (int m = 0; m < 4; ++m)
  #pragma unroll
  for (int n = 0; n < 4; ++n){
    int row0 = bm + wm + m * 16 + l4 * 4;
    int col  = bn + wn + n * 16 + l15;
    #pragma unroll
    for (int r = 0; r < 4; ++r){
      size_t off = (size_t)(row0 + r) * ldc + col;
      float v = acc[m][n][r];
      if (EPI == 0) Cf[off] = v;
      else if (EPI == 2){ float tt = fmaxf(v, 0.f); Cb[off] = f2bf(tt * tt); }
      else if (EPI == 3) Cf[off] = 15.f * tanhf(v * (1.f / 15.f));
    }
  }
}

__global__ __launch_bounds__(256)
void rope_prep_kernel(const float* __restrict__ qkv, const float* __restrict__ cosT,
                      const float* __restrict__ sinT, u16* __restrict__ qb,
                      u16* __restrict__ kb, u16* __restrict__ vb,
                      const float* __restrict__ h12, const float* __restrict__ vgw,
                      const float* __restrict__ ve_emb, const int* __restrict__ idx, int ve){
  int t = blockIdx.x, tid = threadIdx.x;
  int lane = tid & 63, w = tid >> 6;
  const float* row = qkv + (size_t)t * 1280;
  float c = cosT[t * 64 + lane], s = sinT[t * 64 + lane];
  #pragma unroll
  for (int ii = 0; ii < 2; ++ii){
    int item = w + ii * 4;
    const float* src; u16* dst;
    if (item < 6){ src = row + item * HDIM; dst = qb + (size_t)t * DIM + item * HDIM; }
    else { src = row + DIM + (item - 6) * HDIM; dst = kb + (size_t)t * (NKVH * HDIM) + (item - 6) * HDIM; }
    float x1 = src[lane], x2 = src[64 + lane];
    float o1 =  x1 * c + x2 * s;
    float o2 = -x1 * s + x2 * c;
    float ss = o1 * o1 + o2 * o2;
    #pragma unroll
    for (int off = 1; off < 64; off <<= 1) ss += __shfl_xor(ss, off);
    float sc = rsqrtf(ss / (float)HDIM + 1e-6f) * 1.2f;
    dst[lane]      = f2bf(o1 * sc);
    dst[64 + lane] = f2bf(o2 * sc);
  }
  int kvh = tid >> 7, d = tid & 127;
  float val = row[1024 + kvh * HDIM + d];
  if (ve >= 0){
    float g = 0.f;
    #pragma unroll
    for (int j = 0; j < 12; ++j) g += h12[t * 12 + j] * vgw[(ve * 2 + kvh) * 12 + j];
    g = 3.f / (1.f + __expf(-g));
    val += g * ve_emb[((size_t)ve * VOC + idx[t]) * (size_t)(NKVH * HDIM) + kvh * HDIM + d];
  }
  vb[(size_t)t * (NKVH * HDIM) + kvh * HDIM + d] = f2bf(val);
}

__global__ __launch_bounds__(256)
void attn_kernel(const u16* __restrict__ qb, const u16* __restrict__ kb,
                 const u16* __restrict__ vb, u16* __restrict__ yb, int window){
  __shared__ __align__(16) u16 Ks[64][136];
  __shared__ __align__(16) u16 Vt[128][72];
  __shared__ __align__(16) u16 Ps[4][16][72];
  int tid = threadIdx.x, lane = tid & 63, w = tid >> 6;
  int l15 = lane & 15, l4 = lane >> 4;
  int h = blockIdx.y, kvh = h / 3;
  int qs = blockIdx.x * 64;
  bf16x8 qf[4];
  #pragma unroll
  for (int kk = 0; kk < 4; ++kk)
    qf[kk] = *(const bf16x8*)&qb[(size_t)(qs + w * 16 + l15) * DIM + h * HDIM + kk * 32 + l4 * 8];
  f32x4 o[8] = {};
  float m[4]    = {-INFINITY, -INFINITY, -INFINITY, -INFINITY};
  float lsum[4] = {0.f, 0.f, 0.f, 0.f};
  int c0 = 0;
  if (window > 0){ int jm = qs - window; if (jm > 0) c0 = jm >> 6; }
  int c1 = qs >> 6;
  const float scale = 0.08838834764831845f;  // 1/sqrt(128)
  for (int cg = c0; cg <= c1; ++cg){
    int j0 = cg * 64;
    __syncthreads();
    #pragma unroll
    for (int it = 0; it < 4; ++it){
      int p = tid + it * 256, r = p >> 4, cc = (p & 15) * 8;
      *(uint4*)&Ks[r][cc] = *(const uint4*)&kb[(size_t)(j0 + r) * (NKVH * HDIM) + kvh * HDIM + cc];
    }
    {
      int key = tid >> 2, d0 = (tid & 3) * 32;
      const uint4* s4 = (const uint4*)&vb[(size_t)(j0 + key) * (NKVH * HDIM) + kvh * HDIM + d0];
      #pragma unroll
      for (int qq = 0; qq < 4; ++qq){
        uint4 vvv = s4[qq];
        const u16* us = (const u16*)&vvv;
        #pragma unroll
        for (int dd = 0; dd < 8; ++dd) Vt[d0 + qq * 8 + dd][key] = us[dd];
      }
    }
    __syncthreads();
    f32x4 sA[4] = {};
    #pragma unroll
    for (int kk = 0; kk < 4; ++kk){
      #pragma unroll
      for (int n = 0; n < 4; ++n){
        bf16x8 b = *(const bf16x8*)&Ks[n * 16 + l15][kk * 32 + l4 * 8];
        sA[n] = mfma16(qf[kk], b, sA[n]);
      }
    }
    #pragma unroll
    for (int r = 0; r < 4; ++r){
      int qrow = qs + w * 16 + l4 * 4 + r;
      float rowmax = -1e30f;
      #pragma unroll
      for (int n = 0; n < 4; ++n){
        int key = j0 + n * 16 + l15;
        bool ok = (key <= qrow) && (window < 0 || (qrow - key) <= window);
        float sv = ok ? sA[n][r] * scale : -1e30f;
        sA[n][r] = sv;
        rowmax = fmaxf(rowmax, sv);
      }
      #pragma unroll
      for (int off = 1; off < 16; off <<= 1) rowmax = fmaxf(rowmax, __shfl_xor(rowmax, off));
      float mn = fmaxf(m[r], rowmax);
      float alpha = __expf(m[r] - mn);
      float rs = 0.f;
      #pragma unroll
      for (int n = 0; n < 4; ++n){
        float pp = __expf(sA[n][r] - mn);
        sA[n][r] = pp;
        rs += pp;
      }
      #pragma unroll
      for (int off = 1; off < 16; off <<= 1) rs += __shfl_xor(rs, off);
      lsum[r] = lsum[r] * alpha + rs;
      m[r] = mn;
      #pragma unroll
      for (int dt = 0; dt < 8; ++dt) o[dt][r] *= alpha;
    }
    #pragma unroll
    for (int n = 0; n < 4; ++n)
      #pragma unroll
      for (int r = 0; r < 4; ++r)
        Ps[w][l4 * 4 + r][n * 16 + l15] = f2bf(sA[n][r]);
    __syncthreads();
    #pragma unroll
    for (int kk = 0; kk < 2; ++kk){
      bf16x8 a = *(const bf16x8*)&Ps[w][l15][kk * 32 + l4 * 8];
      #pragma unroll
      for (int dt = 0; dt < 8; ++dt){
        bf16x8 b = *(const bf16x8*)&Vt[dt * 16 + l15][kk * 32 + l4 * 8];
        o[dt] = mfma16(a, b, o[dt]);
      }
    }
  }
  #pragma unroll
  for (int dt = 0; dt < 8; ++dt)
    #pragma unroll
    for (int r = 0; r < 4; ++r){
      int rowg = qs + w * 16 + l4 * 4 + r;
      int col  = h * HDIM + dt * 16 + l15;
      yb[(size_t)rowg * DIM + col] = f2bf(o[dt][r] / lsum[r]);
    }
}

__global__ __launch_bounds__(256)
void addcopy_kernel(const float* __restrict__ x, const float* __restrict__ part,
                    float* __restrict__ xb){
  int i = blockIdx.x * 256 + threadIdx.x;
  float v = x[i];
  #pragma unroll
  for (int pp = 0; pp < 4; ++pp) v += part[(size_t)pp * SEQ * DIM + i];
  xb[i] = v;
}

__global__ __launch_bounds__(256)
void final_rms_kernel(const float* __restrict__ x, const float* __restrict__ part,
                      const float* __restrict__ xb, const float* __restrict__ blam,
                      u16* __restrict__ h){
  int t = blockIdx.x;
  float bl = blam[0];
  float v[3], ss = 0.f;
  #pragma unroll
  for (int i = 0; i < 3; ++i){
    int d = threadIdx.x + i * 256;
    size_t o = (size_t)t * DIM + d;
    float val = x[o];
    #pragma unroll
    for (int p = 0; p < 4; ++p) val += part[(size_t)p * SEQ * DIM + o];
    val -= bl * xb[o];
    v[i] = val; ss += val * val;
  }
  ss = blockReduceSum(ss);
  float sc = rsqrtf(ss / (float)DIM + 1e-6f);
  #pragma unroll
  for (int i = 0; i < 3; ++i){
    int d = threadIdx.x + i * 256;
    h[(size_t)t * DIM + d] = f2bf(v[i] * sc);
  }
}

extern "C" void kernel_launch(void* const* d_in, const int* in_sizes, int n_in,
                              void* d_out, int out_size, void* d_ws, size_t ws_size,
                              hipStream_t stream){
  const int*   idx  = (const int*)  d_in[0];
  const float* wte  = (const float*)d_in[1];
  const float* q_w  = (const float*)d_in[2];
  const float* k_w  = (const float*)d_in[3];
  const float* v_w  = (const float*)d_in[4];
  const float* apw  = (const float*)d_in[5];
  const float* vgw  = (const float*)d_in[6];
  const float* fcw  = (const float*)d_in[7];
  const float* mpw  = (const float*)d_in[8];
  const float* vemb = (const float*)d_in[9];
  const float* lmw  = (const float*)d_in[10];
  const float* rls  = (const float*)d_in[11];
  const float* xls  = (const float*)d_in[12];
  const float* sgw  = (const float*)d_in[13];
  const float* slam = (const float*)d_in[14];
  const float* blam = (const float*)d_in[15];

  char* p = (char*)d_ws;
  auto alloc = [&](size_t bytes)->char*{
    char* r = p; p += (bytes + 255) & ~(size_t)255; return r;
  };
  float* cosT = (float*)alloc((size_t)SEQ * 64 * 4);
  float* sinT = (float*)alloc((size_t)SEQ * 64 * 4);
  float* x    = (float*)alloc((size_t)SEQ * DIM * 4);
  float* x0   = (float*)alloc((size_t)SEQ * DIM * 4);
  float* xb   = (float*)alloc((size_t)SEQ * DIM * 4);
  float* qkv  = (float*)alloc((size_t)SEQ * 1280 * 4);
  float* h12  = (float*)alloc((size_t)SEQ * 12 * 4);
  float* pbuf = (float*)alloc((size_t)4 * SEQ * DIM * 4);
  u16* h   = (u16*)alloc((size_t)SEQ * DIM * 2);
  u16* qb  = (u16*)alloc((size_t)SEQ * DIM * 2);
  u16* kb  = (u16*)alloc((size_t)SEQ * NKVH * HDIM * 2);
  u16* vb  = (u16*)alloc((size_t)SEQ * NKVH * HDIM * 2);
  u16* yb  = (u16*)alloc((size_t)SEQ * DIM * 2);
  u16* act = (u16*)alloc((size_t)SEQ * FFN * 2);
  // converted bf16 weights
  u16* wqkv_b = (u16*)alloc((size_t)12 * 1280 * DIM * 2);
  u16* apw_b  = (u16*)alloc((size_t)12 * DIM * DIM * 2);
  u16* fcw_b  = (u16*)alloc((size_t)12 * FFN * DIM * 2);
  u16* mpw_b  = (u16*)alloc((size_t)12 * DIM * FFN * 2);
  u16* lmw_b  = (u16*)alloc((size_t)VOC * DIM * 2);
  bool conv = (size_t)(p - (char*)d_ws) <= ws_size;

  rope_tables_kernel<<<SEQ * 64 / 256, 256, 0, stream>>>(cosT, sinT);
  embed_kernel<<<SEQ, 256, 0, stream>>>(idx, wte, sgw, slam, x, x0);

  if (conv){
    auto cv = [&](const float* s, u16* d, int perSrc, int pitch, int off, int layers){
      int t8 = layers * perSrc / 8;
      convert_kernel<<<(t8 + 255) / 256, 256, 0, stream>>>(s, d, perSrc, pitch, off, t8);
    };
    cv(q_w, wqkv_b, DIM * DIM,        1280 * DIM, 0,          12);
    cv(k_w, wqkv_b, NKVH * HDIM * DIM,1280 * DIM, DIM * DIM,  12);
    cv(v_w, wqkv_b, NKVH * HDIM * DIM,1280 * DIM, 1024 * DIM, 12);
    cv(apw, apw_b,  DIM * DIM,        DIM * DIM,  0,          12);
    cv(fcw, fcw_b,  FFN * DIM,        FFN * DIM,  0,          12);
    cv(mpw, mpw_b,  DIM * FFN,        DIM * FFN,  0,          12);
    cv(lmw, lmw_b,  VOC * DIM,        VOC * DIM,  0,          1);
  }

  static const int WINDOWS[12] = {512, 512, 512, -1, 512, 512, 512, -1, 512, 512, 512, -1};
  for (int l = 0; l < 12; ++l){
    resid_rms_kernel<<<SEQ, 256, 0, stream>>>(x, x0, rls, xls, l, 0, h, h12,
                                              l ? pbuf : nullptr, l ? 4 : 0);
    if (conv){
      gemm_k<0,1><<<dim3(10, 16, 1), 256, 0, stream>>>(h, wqkv_b + (size_t)l * 1280 * DIM,
          qkv, SEQ, 1280, DIM, 1280);
    } else {
      gemm_k<0,0><<<dim3(6, 16, 1), 256, 0, stream>>>(h, q_w + (size_t)l * DIM * DIM,
          qkv, SEQ, DIM, DIM, 1280);
      gemm_k<0,0><<<dim3(2, 16, 1), 256, 0, stream>>>(h, k_w + (size_t)l * NKVH * HDIM * DIM,
          qkv + DIM, SEQ, NKVH * HDIM, DIM, 1280);
      gemm_k<0,0><<<dim3(2, 16, 1), 256, 0, stream>>>(h, v_w + (size_t)l * NKVH * HDIM * DIM,
          qkv + 1024, SEQ, NKVH * HDIM, DIM, 1280);
    }
    int ve = (l & 1) ? (l >> 1) : -1;
    rope_prep_kernel<<<SEQ, 256, 0, stream>>>(qkv, cosT, sinT, qb, kb, vb, h12, vgw, vemb, idx, ve);
    attn_kernel<<<dim3(SEQ / 64, NHEADS), 256, 0, stream>>>(qb, kb, vb, yb, WINDOWS[l]);
    if (conv)
      gemm_k<0,1><<<dim3(6, 16, 2), 256, 0, stream>>>(yb, apw_b + (size_t)l * DIM * DIM,
          pbuf, SEQ, DIM, DIM, DIM);
    else
      gemm_k<0,0><<<dim3(6, 16, 2), 256, 0, stream>>>(yb, apw + (size_t)l * DIM * DIM,
          pbuf, SEQ, DIM, DIM, DIM);
    resid_rms_kernel<<<SEQ, 256, 0, stream>>>(x, x0, rls, xls, l, 1, h, h12, pbuf, 2);
    if (conv)
      gemm_k<2,1><<<dim3(24, 16, 1), 256, 0, stream>>>(h, fcw_b + (size_t)l * FFN * DIM,
          act, SEQ, FFN, DIM, FFN);
    else
      gemm_k<2,0><<<dim3(24, 16, 1), 256, 0, stream>>>(h, fcw + (size_t)l * FFN * DIM,
          act, SEQ, FFN, DIM, FFN);
    if (conv)
      gemm_k<0,1><<<dim3(6, 16, 4), 256, 0, stream>>>(act, mpw_b + (size_t)l * DIM * FFN,
          pbuf, SEQ, DIM, FFN, DIM);
    else
      gemm_k<0,0><<<dim3(6, 16, 4), 256, 0, stream>>>(act, mpw + (size_t)l * DIM * FFN,
          pbuf, SEQ, DIM, FFN, DIM);
    if (l == 5) addcopy_kernel<<<SEQ * DIM / 256, 256, 0, stream>>>(x, pbuf, xb);
  }
  final_rms_kernel<<<SEQ, 256, 0, stream>>>(x, pbuf, xb, blam, h);
  if (conv)
    gemm_k<3,1><<<dim3(VOC / 128, 16, 1), 256, 0, stream>>>(h, lmw_b, d_out, SEQ, VOC, DIM, VOC);
  else
    gemm_k<3,0><<<dim3(VOC / 128, 16, 1), 256, 0, stream>>>(h, lmw, d_out, SEQ, VOC, DIM, VOC);
}